// Round 1
// baseline (589.974 us; speedup 1.0000x reference)
//
#include <hip/hip_runtime.h>

// SelfAttention: X[8192,1024] -> Q,K,V = X@W^T+b ; P=exp(cosine(Q,K)) ; out = P@V / rowsum(P)
// Strategy: all big GEMMs on bf16 MFMA (16x16x32), fp32 accumulate.
//   K0: fp32->bf16 convert (X, Wq, Wk, Wv)
//   K1: QKV GEMM (z=0,1,2). Epilogue: +bias; Q/K -> bf16 + per-row sumsq (fp32 acc, atomics);
//       V stored TRANSPOSED (VT[1024][8192]) so PV GEMM is NT-form.
//   K2: scale Q,K rows by rsqrt(sumsq)  (cosine normalization folded into operands)
//   K3: P = exp(Qn @ Kn^T) bf16 [8192x8192] + row sums (denom) via atomics.
//       scores bounded in [-1,1] -> exp safe without max-subtraction.
//   K4: out = (P @ V) * (1/denom)  (NT GEMM vs VT), fp32 out.
// GEMM core: 128x128 tile, BK=64, 4 waves, global_load_lds width=16, XOR-swizzled LDS.

#define SEQ 8192
#define MID 1024
#define EMB 1024

typedef __attribute__((ext_vector_type(8))) short short8x;
typedef __attribute__((ext_vector_type(4))) float float4x;

__device__ __forceinline__ unsigned short f2bf(float x) {
  union { float f; unsigned u; } v; v.f = x;
  unsigned r = v.u + 0x7FFFu + ((v.u >> 16) & 1u);  // round-to-nearest-even
  return (unsigned short)(r >> 16);
}
__device__ __forceinline__ float bf2f(unsigned short h) {
  union { unsigned u; float f; } v; v.u = ((unsigned)h) << 16;
  return v.f;
}

__device__ __forceinline__ void g2l16(const void* g, unsigned short* lds) {
  __builtin_amdgcn_global_load_lds(
      (const __attribute__((address_space(1))) unsigned int*)g,
      (__attribute__((address_space(3))) unsigned int*)lds, 16, 0, 0);
}

// NT GEMM core: C[128x128] = A[m0.., :K] * B[n0.., :K]^T, A/B bf16 row-major (K contiguous).
// 256 threads = 4 waves; wave (w&1, w>>1) owns a 64x64 quadrant as 4x4 MFMA tiles.
// LDS tiles [128 rows][64 k] bf16, slot kgrp = data_kgrp ^ (row&7) (bank-conflict swizzle);
// staging global addresses are pre-swizzled so global_load_lds (base + lane*16) lands right.
__device__ __forceinline__ void gemm128_nt(
    const unsigned short* __restrict__ A, const unsigned short* __restrict__ B,
    long lda, long ldb, int m0, int n0, int K,
    unsigned short* As, unsigned short* Bs, float4x acc[4][4]) {
  const int tid = threadIdx.x;
  const int w = tid >> 6;
  const int l = tid & 63;
  const int wm = (w & 1) << 6;
  const int wn = (w >> 1) << 6;
  const int srow = l >> 3;             // staging: row-within-8 per lane
  const int skg = (l & 7) ^ srow;      // staging: swizzled k-group to fetch
  const int l15 = l & 15;
  const int l4 = l >> 4;
  const int swz = l15 & 7;             // frag-read row&7

  for (int k0 = 0; k0 < K; k0 += 64) {
    __syncthreads();  // prior compute done before overwriting LDS
#pragma unroll
    for (int r = 0; r < 4; ++r) {
      const int rr = (w * 4 + r) * 8 + srow;               // 0..127
      g2l16(A + (long)(m0 + rr) * lda + k0 + skg * 8, As + (w * 4 + r) * 512);
      g2l16(B + (long)(n0 + rr) * ldb + k0 + skg * 8, Bs + (w * 4 + r) * 512);
    }
    __syncthreads();  // drains vmcnt (global_load_lds) + barrier
#pragma unroll
    for (int ks = 0; ks < 2; ++ks) {
      short8x av[4], bv[4];
      const int kg = ks * 4 + l4;
#pragma unroll
      for (int t = 0; t < 4; ++t) {
        const int ar = wm + t * 16 + l15;
        av[t] = *(const short8x*)(As + ar * 64 + (kg ^ swz) * 8);
        const int br = wn + t * 16 + l15;
        bv[t] = *(const short8x*)(Bs + br * 64 + (kg ^ swz) * 8);
      }
#pragma unroll
      for (int tm = 0; tm < 4; ++tm)
#pragma unroll
        for (int tn = 0; tn < 4; ++tn)
          acc[tm][tn] = __builtin_amdgcn_mfma_f32_16x16x32_bf16(av[tm], bv[tn], acc[tm][tn], 0, 0, 0);
    }
  }
}

__global__ void cvt_kernel(const float* __restrict__ src, unsigned short* __restrict__ dst, int n) {
  int i = (blockIdx.x * 256 + threadIdx.x) * 4;
  if (i + 3 < n) {
    float4 v = *(const float4*)(src + i);
    ushort4 o;
    o.x = f2bf(v.x); o.y = f2bf(v.y); o.z = f2bf(v.z); o.w = f2bf(v.w);
    *(ushort4*)(dst + i) = o;
  }
}

__global__ __launch_bounds__(256) void qkv_kernel(
    const unsigned short* __restrict__ Xb, const unsigned short* __restrict__ Wb,
    const float* __restrict__ bq, const float* __restrict__ bk, const float* __restrict__ bv,
    unsigned short* __restrict__ Qb, unsigned short* __restrict__ Kb,
    unsigned short* __restrict__ VT, float* __restrict__ sumsq) {
  __shared__ unsigned short As[128 * 64];
  __shared__ unsigned short Bs[128 * 64];
  const int z = blockIdx.z;
  const int m0 = blockIdx.y * 128;
  const int n0 = blockIdx.x * 128;
  float4x acc[4][4];
#pragma unroll
  for (int i = 0; i < 4; ++i)
#pragma unroll
    for (int j = 0; j < 4; ++j) acc[i][j] = (float4x){0.f, 0.f, 0.f, 0.f};

  gemm128_nt(Xb, Wb + (long)z * MID * EMB, EMB, EMB, m0, n0, EMB, As, Bs, acc);

  const int l = threadIdx.x & 63, w = threadIdx.x >> 6;
  const int wm = (w & 1) << 6, wn = (w >> 1) << 6;
  const int l15 = l & 15, l4 = l >> 4;
  const float* bias = (z == 0) ? bq : (z == 1) ? bk : bv;
  float bvv[4];
#pragma unroll
  for (int tn = 0; tn < 4; ++tn) bvv[tn] = bias[n0 + wn + tn * 16 + l15];
#pragma unroll
  for (int tm = 0; tm < 4; ++tm)
#pragma unroll
    for (int tn = 0; tn < 4; ++tn)
#pragma unroll
      for (int r = 0; r < 4; ++r) acc[tm][tn][r] += bvv[tn];

  if (z < 2) {
    unsigned short* O = z ? Kb : Qb;
    float* ss = sumsq + (long)z * SEQ;
    // per-row sum of squares (fp32, pre-bf16-rounding) -> atomics
#pragma unroll
    for (int tm = 0; tm < 4; ++tm)
#pragma unroll
      for (int r = 0; r < 4; ++r) {
        float s = 0.f;
#pragma unroll
        for (int tn = 0; tn < 4; ++tn) { float v = acc[tm][tn][r]; s += v * v; }
        s += __shfl_xor(s, 1); s += __shfl_xor(s, 2);
        s += __shfl_xor(s, 4); s += __shfl_xor(s, 8);
        if (l15 == 0) atomicAdd(ss + m0 + wm + tm * 16 + l4 * 4 + r, s);
      }
    // bf16 store, pair-packed (even lane stores cols c,c+1 as one dword)
#pragma unroll
    for (int tm = 0; tm < 4; ++tm)
#pragma unroll
      for (int tn = 0; tn < 4; ++tn)
#pragma unroll
        for (int r = 0; r < 4; ++r) {
          float v = acc[tm][tn][r];
          float po = __shfl_xor(v, 1);
          if (!(l & 1)) {
            const int row = m0 + wm + tm * 16 + l4 * 4 + r;
            const int col = n0 + wn + tn * 16 + l15;
            unsigned pk = (unsigned)f2bf(v) | ((unsigned)f2bf(po) << 16);
            *(unsigned*)(O + (long)row * MID + col) = pk;
          }
        }
  } else {
    // V: store transposed VT[n][m]; lane holds 4 consecutive rows -> 8B packed store
#pragma unroll
    for (int tm = 0; tm < 4; ++tm)
#pragma unroll
      for (int tn = 0; tn < 4; ++tn) {
        const int nn = n0 + wn + tn * 16 + l15;
        const int mm = m0 + wm + tm * 16 + l4 * 4;
        ushort4 pk;
        pk.x = f2bf(acc[tm][tn][0]);
        pk.y = f2bf(acc[tm][tn][1]);
        pk.z = f2bf(acc[tm][tn][2]);
        pk.w = f2bf(acc[tm][tn][3]);
        *(ushort4*)(VT + (long)nn * SEQ + mm) = pk;
      }
  }
}

__global__ void scale_kernel(unsigned short* __restrict__ Qb, unsigned short* __restrict__ Kb,
                             const float* __restrict__ sumsq) {
  const int row = blockIdx.x;
  unsigned short* buf = blockIdx.y ? Kb : Qb;
  const float inv = rsqrtf(sumsq[blockIdx.y * SEQ + row]);
  const int i = threadIdx.x * 4;
  ushort4* p = (ushort4*)(buf + (long)row * MID + i);
  ushort4 v = *p;
  v.x = f2bf(bf2f(v.x) * inv);
  v.y = f2bf(bf2f(v.y) * inv);
  v.z = f2bf(bf2f(v.z) * inv);
  v.w = f2bf(bf2f(v.w) * inv);
  *p = v;
}

__global__ __launch_bounds__(256) void score_kernel(
    const unsigned short* __restrict__ Qb, const unsigned short* __restrict__ Kb,
    unsigned short* __restrict__ P, float* __restrict__ denom) {
  __shared__ unsigned short As[128 * 64];
  __shared__ unsigned short Bs[128 * 64];
  const int m0 = blockIdx.y * 128;
  const int n0 = blockIdx.x * 128;
  float4x acc[4][4];
#pragma unroll
  for (int i = 0; i < 4; ++i)
#pragma unroll
    for (int j = 0; j < 4; ++j) acc[i][j] = (float4x){0.f, 0.f, 0.f, 0.f};

  gemm128_nt(Qb, Kb, MID, MID, m0, n0, MID, As, Bs, acc);

  const int l = threadIdx.x & 63, w = threadIdx.x >> 6;
  const int wm = (w & 1) << 6, wn = (w >> 1) << 6;
  const int l15 = l & 15, l4 = l >> 4;
  // scores in [-1,1] -> exp safe without max subtraction; softmax = e / rowsum(e)
#pragma unroll
  for (int tm = 0; tm < 4; ++tm)
#pragma unroll
    for (int tn = 0; tn < 4; ++tn)
#pragma unroll
      for (int r = 0; r < 4; ++r) acc[tm][tn][r] = __expf(acc[tm][tn][r]);

#pragma unroll
  for (int tm = 0; tm < 4; ++tm)
#pragma unroll
    for (int r = 0; r < 4; ++r) {
      float s = 0.f;
#pragma unroll
      for (int tn = 0; tn < 4; ++tn) s += acc[tm][tn][r];
      s += __shfl_xor(s, 1); s += __shfl_xor(s, 2);
      s += __shfl_xor(s, 4); s += __shfl_xor(s, 8);
      if (l15 == 0) atomicAdd(denom + m0 + wm + tm * 16 + l4 * 4 + r, s);
    }
#pragma unroll
  for (int tm = 0; tm < 4; ++tm)
#pragma unroll
    for (int tn = 0; tn < 4; ++tn)
#pragma unroll
      for (int r = 0; r < 4; ++r) {
        float v = acc[tm][tn][r];
        float po = __shfl_xor(v, 1);
        if (!(l & 1)) {
          const int row = m0 + wm + tm * 16 + l4 * 4 + r;
          const int col = n0 + wn + tn * 16 + l15;
          unsigned pk = (unsigned)f2bf(v) | ((unsigned)f2bf(po) << 16);
          *(unsigned*)(P + (long)row * SEQ + col) = pk;
        }
      }
}

__global__ __launch_bounds__(256) void out_kernel(
    const unsigned short* __restrict__ P, const unsigned short* __restrict__ VT,
    const float* __restrict__ denom, float* __restrict__ out) {
  __shared__ unsigned short As[128 * 64];
  __shared__ unsigned short Bs[128 * 64];
  const int m0 = blockIdx.y * 128;
  const int n0 = blockIdx.x * 128;
  float4x acc[4][4];
#pragma unroll
  for (int i = 0; i < 4; ++i)
#pragma unroll
    for (int j = 0; j < 4; ++j) acc[i][j] = (float4x){0.f, 0.f, 0.f, 0.f};

  gemm128_nt(P, VT, SEQ, SEQ, m0, n0, SEQ, As, Bs, acc);

  const int l = threadIdx.x & 63, w = threadIdx.x >> 6;
  const int wm = (w & 1) << 6, wn = (w >> 1) << 6;
  const int l15 = l & 15, l4 = l >> 4;
#pragma unroll
  for (int tm = 0; tm < 4; ++tm)
#pragma unroll
    for (int r = 0; r < 4; ++r) {
      const int row = m0 + wm + tm * 16 + l4 * 4 + r;
      const float inv = 1.0f / denom[row];
#pragma unroll
      for (int tn = 0; tn < 4; ++tn) {
        const int col = n0 + wn + tn * 16 + l15;
        out[(long)row * MID + col] = acc[tm][tn][r] * inv;
      }
    }
}

extern "C" void kernel_launch(void* const* d_in, const int* in_sizes, int n_in,
                              void* d_out, int out_size, void* d_ws, size_t ws_size,
                              hipStream_t stream) {
  const float* X  = (const float*)d_in[0];
  const float* Wq = (const float*)d_in[1];
  const float* bq = (const float*)d_in[2];
  const float* Wk = (const float*)d_in[3];
  const float* bk = (const float*)d_in[4];
  const float* Wv = (const float*)d_in[5];
  const float* bv = (const float*)d_in[6];

  // workspace layout (bytes). Xb/Wb alias the P region: they are dead before K3 writes P.
  //  [0,16M)   Qb bf16 [8192][1024]
  //  [16M,32M) Kb bf16
  //  [32M,48M) VT bf16 [1024][8192]   (V transposed)
  //  [48M,..)  sumsq_q[8192], sumsq_k[8192], denom[8192]  fp32
  //  [49M,177M) P bf16 [8192][8192];  Xb at 49M (16M), Wb at 65M (6M) alias inside
  char* wsb = (char*)d_ws;
  const size_t MB = 1ull << 20;
  unsigned short* Qb = (unsigned short*)(wsb);
  unsigned short* Kb = (unsigned short*)(wsb + 16 * MB);
  unsigned short* VT = (unsigned short*)(wsb + 32 * MB);
  float* sums        = (float*)(wsb + 48 * MB);
  float* denom       = sums + 2 * SEQ;
  unsigned short* P  = (unsigned short*)(wsb + 49 * MB);
  unsigned short* Xb = (unsigned short*)(wsb + 49 * MB);
  unsigned short* Wb = (unsigned short*)(wsb + 65 * MB);

  hipMemsetAsync(sums, 0, 3 * SEQ * sizeof(float), stream);

  cvt_kernel<<<SEQ * EMB / 1024, 256, 0, stream>>>(X, Xb, SEQ * EMB);
  cvt_kernel<<<MID * EMB / 1024, 256, 0, stream>>>(Wq, Wb, MID * EMB);
  cvt_kernel<<<MID * EMB / 1024, 256, 0, stream>>>(Wk, Wb + MID * EMB, MID * EMB);
  cvt_kernel<<<MID * EMB / 1024, 256, 0, stream>>>(Wv, Wb + 2 * MID * EMB, MID * EMB);

  qkv_kernel<<<dim3(MID / 128, SEQ / 128, 3), 256, 0, stream>>>(Xb, Wb, bq, bk, bv, Qb, Kb, VT, sums);
  scale_kernel<<<dim3(SEQ, 2), 256, 0, stream>>>(Qb, Kb, sums);
  score_kernel<<<dim3(SEQ / 128, SEQ / 128), 256, 0, stream>>>(Qb, Kb, P, denom);
  out_kernel<<<dim3(MID / 128, SEQ / 128), 256, 0, stream>>>(P, VT, denom, (float*)d_out);
}

// Round 2
// 564.083 us; speedup vs baseline: 1.0459x; 1.0459x over previous
//
#include <hip/hip_runtime.h>

// SelfAttention: X[8192,1024] -> Q,K,V = X@W^T+b ; P=exp(cosine(Q,K)) ; out = P@V / rowsum(P)
// R2 changes vs R1:
//  - score/qkv epilogues: LDS-transpose -> 256B-per-row full-line stores
//    (R1's 32B segments caused ~128MB write-allocate RMW FETCH in score_kernel)
//  - row sums (denom / sumsq) computed from the LDS readback (4 shuffles/row, not 8)
//  - scale_kernel eliminated: cosine norm folded into score epilogue (invq*invk before exp)
//  - out_kernel grid transposed (m fast) so the 8 n-blocks of one P-stripe land on one XCD
//  - weight cvt merged into one launch

#define SEQ 8192
#define MID 1024
#define EMB 1024

typedef __attribute__((ext_vector_type(8))) short short8x;
typedef __attribute__((ext_vector_type(4))) float float4x;

__device__ __forceinline__ unsigned short f2bf(float x) {
  union { float f; unsigned u; } v; v.f = x;
  unsigned r = v.u + 0x7FFFu + ((v.u >> 16) & 1u);  // round-to-nearest-even
  return (unsigned short)(r >> 16);
}
__device__ __forceinline__ float bf2f(unsigned short h) {
  union { unsigned u; float f; } v; v.u = ((unsigned)h) << 16;
  return v.f;
}

__device__ __forceinline__ void g2l16(const void* g, unsigned short* lds) {
  __builtin_amdgcn_global_load_lds(
      (const __attribute__((address_space(1))) unsigned int*)g,
      (__attribute__((address_space(3))) unsigned int*)lds, 16, 0, 0);
}

// NT GEMM core: C[128x128] = A[m0.., :K] * B[n0.., :K]^T, A/B bf16 row-major (K contiguous).
// 256 threads = 4 waves; wave (w&1, w>>1) owns a 64x64 quadrant as 4x4 MFMA tiles.
// LDS tiles [128 rows][64 k] bf16, slot kgrp = data_kgrp ^ (row&7) (bank swizzle);
// staging global addresses pre-swizzled so global_load_lds (base + lane*16) lands right.
__device__ __forceinline__ void gemm128_nt(
    const unsigned short* __restrict__ A, const unsigned short* __restrict__ B,
    long lda, long ldb, int m0, int n0, int K,
    unsigned short* As, unsigned short* Bs, float4x acc[4][4]) {
  const int tid = threadIdx.x;
  const int w = tid >> 6;
  const int l = tid & 63;
  const int wm = (w & 1) << 6;
  const int wn = (w >> 1) << 6;
  const int srow = l >> 3;             // staging: row-within-8 per lane
  const int skg = (l & 7) ^ srow;      // staging: swizzled k-group to fetch
  const int l15 = l & 15;
  const int l4 = l >> 4;
  const int swz = l15 & 7;             // frag-read row&7

  for (int k0 = 0; k0 < K; k0 += 64) {
    __syncthreads();  // prior compute done before overwriting LDS
#pragma unroll
    for (int r = 0; r < 4; ++r) {
      const int rr = (w * 4 + r) * 8 + srow;               // 0..127
      g2l16(A + (long)(m0 + rr) * lda + k0 + skg * 8, As + (w * 4 + r) * 512);
      g2l16(B + (long)(n0 + rr) * ldb + k0 + skg * 8, Bs + (w * 4 + r) * 512);
    }
    __syncthreads();  // drains vmcnt (global_load_lds) + barrier
#pragma unroll
    for (int ks = 0; ks < 2; ++ks) {
      short8x av[4], bv[4];
      const int kg = ks * 4 + l4;
#pragma unroll
      for (int t = 0; t < 4; ++t) {
        const int ar = wm + t * 16 + l15;
        av[t] = *(const short8x*)(As + ar * 64 + (kg ^ swz) * 8);
        const int br = wn + t * 16 + l15;
        bv[t] = *(const short8x*)(Bs + br * 64 + (kg ^ swz) * 8);
      }
#pragma unroll
      for (int tm = 0; tm < 4; ++tm)
#pragma unroll
        for (int tn = 0; tn < 4; ++tn)
          acc[tm][tn] = __builtin_amdgcn_mfma_f32_16x16x32_bf16(av[tm], bv[tn], acc[tm][tn], 0, 0, 0);
    }
  }
}

__global__ void cvt_kernel(const float* __restrict__ src, unsigned short* __restrict__ dst, int n) {
  int i = (blockIdx.x * 256 + threadIdx.x) * 4;
  if (i + 3 < n) {
    float4 v = *(const float4*)(src + i);
    ushort4 o;
    o.x = f2bf(v.x); o.y = f2bf(v.y); o.z = f2bf(v.z); o.w = f2bf(v.w);
    *(ushort4*)(dst + i) = o;
  }
}

// one launch for all three weights (each MID*EMB elements, 4 per thread)
__global__ void cvtw_kernel(const float* __restrict__ wq, const float* __restrict__ wk,
                            const float* __restrict__ wv, unsigned short* __restrict__ dst) {
  int idx4 = (blockIdx.x * 256 + threadIdx.x) * 4;
  const int per = MID * EMB;
  int t = idx4 / per;
  int off = idx4 - t * per;
  const float* src = (t == 0) ? wq : (t == 1) ? wk : wv;
  float4 v = *(const float4*)(src + off);
  ushort4 o;
  o.x = f2bf(v.x); o.y = f2bf(v.y); o.z = f2bf(v.z); o.w = f2bf(v.w);
  *(ushort4*)(dst + idx4) = o;
}

__global__ __launch_bounds__(256) void qkv_kernel(
    const unsigned short* __restrict__ Xb, const unsigned short* __restrict__ Wb,
    const float* __restrict__ bq, const float* __restrict__ bk, const float* __restrict__ bv,
    unsigned short* __restrict__ Qb, unsigned short* __restrict__ Kb,
    unsigned short* __restrict__ VT, float* __restrict__ sumsq) {
  __shared__ unsigned short smem[16384];  // 32 KB: As/Bs during GEMM, transpose tile in epilogue
  unsigned short* As = smem;
  unsigned short* Bs = smem + 8192;
  const int z = blockIdx.z;
  const int m0 = blockIdx.y * 128;
  const int n0 = blockIdx.x * 128;
  float4x acc[4][4];
#pragma unroll
  for (int i = 0; i < 4; ++i)
#pragma unroll
    for (int j = 0; j < 4; ++j) acc[i][j] = (float4x){0.f, 0.f, 0.f, 0.f};

  gemm128_nt(Xb, Wb + (long)z * MID * EMB, EMB, EMB, m0, n0, EMB, As, Bs, acc);

  const int tid = threadIdx.x;
  const int l = tid & 63, w = tid >> 6;
  const int wm = (w & 1) << 6, wn = (w >> 1) << 6;
  const int l15 = l & 15, l4 = l >> 4;
  const float* bias = (z == 0) ? bq : (z == 1) ? bk : bv;
  float bvv[4];
#pragma unroll
  for (int tn = 0; tn < 4; ++tn) bvv[tn] = bias[n0 + wn + tn * 16 + l15];
#pragma unroll
  for (int tm = 0; tm < 4; ++tm)
#pragma unroll
    for (int tn = 0; tn < 4; ++tn)
#pragma unroll
      for (int r = 0; r < 4; ++r) acc[tm][tn][r] += bvv[tn];

  __syncthreads();  // all waves done reading As/Bs

  if (z < 2) {
    // [row][col] bf16 tile, chunk ^= row&7 swizzle; pack col-pairs via shfl
#pragma unroll
    for (int tm = 0; tm < 4; ++tm)
#pragma unroll
      for (int tn = 0; tn < 4; ++tn)
#pragma unroll
        for (int r = 0; r < 4; ++r) {
          float v = acc[tm][tn][r];
          float po = __shfl_xor(v, 1);
          if (!(l & 1)) {
            const int rrow = wm + tm * 16 + l4 * 4 + r;
            const int rcol = wn + tn * 16 + l15;  // even
            const int chunk = (rcol >> 3) ^ (rrow & 7);
            unsigned pk = (unsigned)f2bf(v) | ((unsigned)f2bf(po) << 16);
            *(unsigned*)(smem + rrow * 128 + (chunk << 3) + (rcol & 7)) = pk;
          }
        }
    __syncthreads();
    unsigned short* O = z ? Kb : Qb;
    float* ss = sumsq + (long)z * SEQ;
#pragma unroll
    for (int round = 0; round < 8; ++round) {
      const int row = round * 16 + (tid >> 4);
      const int c = tid & 15;
      short8x vv = *(const short8x*)(smem + row * 128 + ((c ^ (row & 7)) << 3));
      *(short8x*)(O + (long)(m0 + row) * MID + n0 + c * 8) = vv;
      float s = 0.f;
#pragma unroll
      for (int j = 0; j < 8; ++j) { float f = bf2f((unsigned short)vv[j]); s += f * f; }
      s += __shfl_xor(s, 1); s += __shfl_xor(s, 2);
      s += __shfl_xor(s, 4); s += __shfl_xor(s, 8);
      if (c == 0) atomicAdd(ss + m0 + row, s);
    }
  } else {
    // V transposed: LDS tile [nn][mm]; 4 consecutive mm per lane pack in-register (no shfl)
#pragma unroll
    for (int tm = 0; tm < 4; ++tm)
#pragma unroll
      for (int tn = 0; tn < 4; ++tn) {
        const int nn = wn + tn * 16 + l15;
        const int mm = wm + tm * 16 + l4 * 4;
        const int chunk = (mm >> 3) ^ (nn & 7);
        ushort4 pk;
        pk.x = f2bf(acc[tm][tn][0]);
        pk.y = f2bf(acc[tm][tn][1]);
        pk.z = f2bf(acc[tm][tn][2]);
        pk.w = f2bf(acc[tm][tn][3]);
        *(ushort4*)(smem + nn * 128 + (chunk << 3) + (mm & 7)) = pk;
      }
    __syncthreads();
#pragma unroll
    for (int round = 0; round < 8; ++round) {
      const int nn = round * 16 + (tid >> 4);
      const int c = tid & 15;
      short8x vv = *(const short8x*)(smem + nn * 128 + ((c ^ (nn & 7)) << 3));
      *(short8x*)(VT + (long)(n0 + nn) * SEQ + m0 + c * 8) = vv;
    }
  }
}

__global__ __launch_bounds__(256) void score_kernel(
    const unsigned short* __restrict__ Qb, const unsigned short* __restrict__ Kb,
    const float* __restrict__ sumsq,
    unsigned short* __restrict__ P, float* __restrict__ denom) {
  __shared__ unsigned short smem[16384];
  unsigned short* As = smem;
  unsigned short* Bs = smem + 8192;
  const int m0 = blockIdx.y * 128;
  const int n0 = blockIdx.x * 128;
  float4x acc[4][4];
#pragma unroll
  for (int i = 0; i < 4; ++i)
#pragma unroll
    for (int j = 0; j < 4; ++j) acc[i][j] = (float4x){0.f, 0.f, 0.f, 0.f};

  gemm128_nt(Qb, Kb, MID, MID, m0, n0, MID, As, Bs, acc);

  const int tid = threadIdx.x;
  const int l = tid & 63, w = tid >> 6;
  const int wm = (w & 1) << 6, wn = (w >> 1) << 6;
  const int l15 = l & 15, l4 = l >> 4;

  // cosine normalization folded here (scale_kernel eliminated)
  float iq[4][4];
#pragma unroll
  for (int tm = 0; tm < 4; ++tm)
#pragma unroll
    for (int r = 0; r < 4; ++r)
      iq[tm][r] = rsqrtf(sumsq[m0 + wm + tm * 16 + l4 * 4 + r]);
  float ik[4];
#pragma unroll
  for (int tn = 0; tn < 4; ++tn)
    ik[tn] = rsqrtf(sumsq[SEQ + n0 + wn + tn * 16 + l15]);

  __syncthreads();  // all waves done reading As/Bs

  // exp(scores) -> LDS tile [row][col] bf16, then full-line stores + row sums
#pragma unroll
  for (int tm = 0; tm < 4; ++tm)
#pragma unroll
    for (int tn = 0; tn < 4; ++tn)
#pragma unroll
      for (int r = 0; r < 4; ++r) {
        float v = __expf(acc[tm][tn][r] * iq[tm][r] * ik[tn]);
        float po = __shfl_xor(v, 1);
        if (!(l & 1)) {
          const int rrow = wm + tm * 16 + l4 * 4 + r;
          const int rcol = wn + tn * 16 + l15;  // even
          const int chunk = (rcol >> 3) ^ (rrow & 7);
          unsigned pk = (unsigned)f2bf(v) | ((unsigned)f2bf(po) << 16);
          *(unsigned*)(smem + rrow * 128 + (chunk << 3) + (rcol & 7)) = pk;
        }
      }
  __syncthreads();
#pragma unroll
  for (int round = 0; round < 8; ++round) {
    const int row = round * 16 + (tid >> 4);
    const int c = tid & 15;
    short8x vv = *(const short8x*)(smem + row * 128 + ((c ^ (row & 7)) << 3));
    *(short8x*)(P + (long)(m0 + row) * SEQ + n0 + c * 8) = vv;
    float s = 0.f;
#pragma unroll
    for (int j = 0; j < 8; ++j) s += bf2f((unsigned short)vv[j]);
    s += __shfl_xor(s, 1); s += __shfl_xor(s, 2);
    s += __shfl_xor(s, 4); s += __shfl_xor(s, 8);
    if (c == 0) atomicAdd(denom + m0 + row, s);
  }
}

__global__ __launch_bounds__(256) void out_kernel(
    const unsigned short* __restrict__ P, const unsigned short* __restrict__ VT,
    const float* __restrict__ denom, float* __restrict__ out) {
  __shared__ unsigned short smem[16384];
  unsigned short* As = smem;
  unsigned short* Bs = smem + 8192;
  // grid: x = m (fast, 64), y = n (8) -> the 8 n-blocks of one m-stripe have
  // linear ids = m + 64*n, all congruent mod 8 -> same XCD -> P stripe L2-shared.
  const int m0 = blockIdx.x * 128;
  const int n0 = blockIdx.y * 128;
  float4x acc[4][4];
#pragma unroll
  for (int i = 0; i < 4; ++i)
#pragma unroll
    for (int j = 0; j < 4; ++j) acc[i][j] = (float4x){0.f, 0.f, 0.f, 0.f};

  gemm128_nt(P, VT, SEQ, SEQ, m0, n0, SEQ, As, Bs, acc);

  const int l = threadIdx.x & 63, w = threadIdx.x >> 6;
  const int wm = (w & 1) << 6, wn = (w >> 1) << 6;
  const int l15 = l & 15, l4 = l >> 4;
#pragma unroll
  for (int tm = 0; tm < 4; ++tm)
#pragma unroll
    for (int r = 0; r < 4; ++r) {
      const int row = m0 + wm + tm * 16 + l4 * 4 + r;
      const float inv = 1.0f / denom[row];
#pragma unroll
      for (int tn = 0; tn < 4; ++tn) {
        const int col = n0 + wn + tn * 16 + l15;
        out[(long)row * MID + col] = acc[tm][tn][r] * inv;
      }
    }
}

extern "C" void kernel_launch(void* const* d_in, const int* in_sizes, int n_in,
                              void* d_out, int out_size, void* d_ws, size_t ws_size,
                              hipStream_t stream) {
  const float* X  = (const float*)d_in[0];
  const float* Wq = (const float*)d_in[1];
  const float* bq = (const float*)d_in[2];
  const float* Wk = (const float*)d_in[3];
  const float* bk = (const float*)d_in[4];
  const float* Wv = (const float*)d_in[5];
  const float* bv = (const float*)d_in[6];

  // workspace layout (bytes). Xb/Wb alias the P region: dead before score writes P.
  //  [0,16M)   Qb bf16 [8192][1024]   (unnormalized)
  //  [16M,32M) Kb bf16
  //  [32M,48M) VT bf16 [1024][8192]
  //  [48M,..)  sumsq_q[8192], sumsq_k[8192], denom[8192]  fp32
  //  [49M,177M) P bf16 [8192][8192];  Xb at 49M (16M), Wb at 65M (6M) alias inside
  char* wsb = (char*)d_ws;
  const size_t MB = 1ull << 20;
  unsigned short* Qb = (unsigned short*)(wsb);
  unsigned short* Kb = (unsigned short*)(wsb + 16 * MB);
  unsigned short* VT = (unsigned short*)(wsb + 32 * MB);
  float* sums        = (float*)(wsb + 48 * MB);
  float* denom       = sums + 2 * SEQ;
  unsigned short* P  = (unsigned short*)(wsb + 49 * MB);
  unsigned short* Xb = (unsigned short*)(wsb + 49 * MB);
  unsigned short* Wb = (unsigned short*)(wsb + 65 * MB);

  hipMemsetAsync(sums, 0, 3 * SEQ * sizeof(float), stream);

  cvt_kernel<<<SEQ * EMB / 1024, 256, 0, stream>>>(X, Xb, SEQ * EMB);
  cvtw_kernel<<<3 * MID * EMB / 1024, 256, 0, stream>>>(Wq, Wk, Wv, Wb);

  qkv_kernel<<<dim3(MID / 128, SEQ / 128, 3), 256, 0, stream>>>(Xb, Wb, bq, bk, bv, Qb, Kb, VT, sums);
  score_kernel<<<dim3(SEQ / 128, SEQ / 128), 256, 0, stream>>>(Qb, Kb, sums, P, denom);
  out_kernel<<<dim3(SEQ / 128, MID / 128), 256, 0, stream>>>(P, VT, denom, (float*)d_out);
}

// Round 3
// 532.389 us; speedup vs baseline: 1.1082x; 1.0595x over previous
//
#include <hip/hip_runtime.h>

// SelfAttention: X[8192,1024] -> Q,K,V = X@W^T+b ; P=exp(cosine(Q,K)) ; out = P@V / rowsum(P)
// R3 change vs R2: GEMM core switched 16x16x32 -> 32x32x16 MFMA (2382 vs 2075 TF ubench
// ceiling, half the MFMA instruction count per flop -> more issue slots for VALU/loads).
// Wave quadrant 64x64 = 2x2 tiles of 32x32; acc = 4 x float16 (64 AGPRs, unchanged).
// C/D layout: col=lane&31, row=(reg&3)+8*(reg>>2)+4*(lane>>5)  [m74/m101 verified]
// A/B frag:   row=lane&31, k=(lane>>5)*8+i                      [same family as 16x16]

#define SEQ 8192
#define MID 1024
#define EMB 1024

typedef __attribute__((ext_vector_type(8))) short short8x;
typedef __attribute__((ext_vector_type(16))) float float16x;

__device__ __forceinline__ unsigned short f2bf(float x) {
  union { float f; unsigned u; } v; v.f = x;
  unsigned r = v.u + 0x7FFFu + ((v.u >> 16) & 1u);  // round-to-nearest-even
  return (unsigned short)(r >> 16);
}
__device__ __forceinline__ float bf2f(unsigned short h) {
  union { unsigned u; float f; } v; v.u = ((unsigned)h) << 16;
  return v.f;
}

__device__ __forceinline__ void g2l16(const void* g, unsigned short* lds) {
  __builtin_amdgcn_global_load_lds(
      (const __attribute__((address_space(1))) unsigned int*)g,
      (__attribute__((address_space(3))) unsigned int*)lds, 16, 0, 0);
}

// NT GEMM core: C[128x128] = A[m0.., :K] * B[n0.., :K]^T, A/B bf16 row-major (K contiguous).
// 256 threads = 4 waves; wave (w&1, w>>1) owns a 64x64 quadrant as 2x2 MFMA 32x32 tiles.
// LDS tiles [128 rows][64 k] bf16, slot chunk = data_kgrp ^ (row&7) (bank swizzle);
// staging global addresses pre-swizzled so global_load_lds (base + lane*16) lands right.
__device__ __forceinline__ void gemm128_nt(
    const unsigned short* __restrict__ A, const unsigned short* __restrict__ B,
    long lda, long ldb, int m0, int n0, int K,
    unsigned short* As, unsigned short* Bs, float16x acc[2][2]) {
  const int tid = threadIdx.x;
  const int w = tid >> 6;
  const int l = tid & 63;
  const int wm = (w & 1) << 6;
  const int wn = (w >> 1) << 6;
  const int srow = l >> 3;             // staging: row-within-8 per lane
  const int skg = (l & 7) ^ srow;      // staging: swizzled k-group to fetch
  const int l31 = l & 31;
  const int lh = l >> 5;               // k-half selector
  const int swz = l31 & 7;             // frag-read row&7

  for (int k0 = 0; k0 < K; k0 += 64) {
    __syncthreads();  // prior compute done before overwriting LDS
#pragma unroll
    for (int r = 0; r < 4; ++r) {
      const int rr = (w * 4 + r) * 8 + srow;               // 0..127
      g2l16(A + (long)(m0 + rr) * lda + k0 + skg * 8, As + (w * 4 + r) * 512);
      g2l16(B + (long)(n0 + rr) * ldb + k0 + skg * 8, Bs + (w * 4 + r) * 512);
    }
    __syncthreads();  // drains vmcnt (global_load_lds) + barrier
#pragma unroll
    for (int ks = 0; ks < 4; ++ks) {
      const int kg = ks * 2 + lh;
      short8x av[2], bv[2];
#pragma unroll
      for (int t = 0; t < 2; ++t) {
        const int ar = wm + t * 32 + l31;
        av[t] = *(const short8x*)(As + ar * 64 + ((kg ^ swz) << 3));
        const int br = wn + t * 32 + l31;
        bv[t] = *(const short8x*)(Bs + br * 64 + ((kg ^ swz) << 3));
      }
#pragma unroll
      for (int tm = 0; tm < 2; ++tm)
#pragma unroll
        for (int tn = 0; tn < 2; ++tn)
          acc[tm][tn] = __builtin_amdgcn_mfma_f32_32x32x16_bf16(av[tm], bv[tn], acc[tm][tn], 0, 0, 0);
    }
  }
}

__global__ void cvt_kernel(const float* __restrict__ src, unsigned short* __restrict__ dst, int n) {
  int i = (blockIdx.x * 256 + threadIdx.x) * 4;
  if (i + 3 < n) {
    float4 v = *(const float4*)(src + i);
    ushort4 o;
    o.x = f2bf(v.x); o.y = f2bf(v.y); o.z = f2bf(v.z); o.w = f2bf(v.w);
    *(ushort4*)(dst + i) = o;
  }
}

// one launch for all three weights (each MID*EMB elements, 4 per thread)
__global__ void cvtw_kernel(const float* __restrict__ wq, const float* __restrict__ wk,
                            const float* __restrict__ wv, unsigned short* __restrict__ dst) {
  int idx4 = (blockIdx.x * 256 + threadIdx.x) * 4;
  const int per = MID * EMB;
  int t = idx4 / per;
  int off = idx4 - t * per;
  const float* src = (t == 0) ? wq : (t == 1) ? wk : wv;
  float4 v = *(const float4*)(src + off);
  ushort4 o;
  o.x = f2bf(v.x); o.y = f2bf(v.y); o.z = f2bf(v.z); o.w = f2bf(v.w);
  *(ushort4*)(dst + idx4) = o;
}

__global__ __launch_bounds__(256) void qkv_kernel(
    const unsigned short* __restrict__ Xb, const unsigned short* __restrict__ Wb,
    const float* __restrict__ bq, const float* __restrict__ bk, const float* __restrict__ bv,
    unsigned short* __restrict__ Qb, unsigned short* __restrict__ Kb,
    unsigned short* __restrict__ VT, float* __restrict__ sumsq) {
  __shared__ unsigned short smem[16384];  // 32 KB: As/Bs during GEMM, transpose tile in epilogue
  unsigned short* As = smem;
  unsigned short* Bs = smem + 8192;
  const int z = blockIdx.z;
  const int m0 = blockIdx.y * 128;
  const int n0 = blockIdx.x * 128;
  float16x acc[2][2];
#pragma unroll
  for (int i = 0; i < 2; ++i)
#pragma unroll
    for (int j = 0; j < 2; ++j)
#pragma unroll
      for (int e = 0; e < 16; ++e) acc[i][j][e] = 0.f;

  gemm128_nt(Xb, Wb + (long)z * MID * EMB, EMB, EMB, m0, n0, EMB, As, Bs, acc);

  const int tid = threadIdx.x;
  const int l = tid & 63, w = tid >> 6;
  const int wm = (w & 1) << 6, wn = (w >> 1) << 6;
  const int l31 = l & 31, lh = l >> 5;
  const float* bias = (z == 0) ? bq : (z == 1) ? bk : bv;
  float bvv[2];
#pragma unroll
  for (int tn = 0; tn < 2; ++tn) bvv[tn] = bias[n0 + wn + tn * 32 + l31];
#pragma unroll
  for (int tm = 0; tm < 2; ++tm)
#pragma unroll
    for (int tn = 0; tn < 2; ++tn)
#pragma unroll
      for (int r = 0; r < 16; ++r) acc[tm][tn][r] += bvv[tn];

  __syncthreads();  // all waves done reading As/Bs

  if (z < 2) {
    // [row][col] bf16 tile, chunk ^= row&7 swizzle; pack col-pairs via shfl
#pragma unroll
    for (int tm = 0; tm < 2; ++tm)
#pragma unroll
      for (int tn = 0; tn < 2; ++tn) {
        const int rcol = wn + tn * 32 + l31;
#pragma unroll
        for (int r = 0; r < 16; ++r) {
          float v = acc[tm][tn][r];
          float po = __shfl_xor(v, 1);
          if (!(l & 1)) {
            const int rrow = wm + tm * 32 + (r & 3) + 8 * (r >> 2) + 4 * lh;
            const int chunk = (rcol >> 3) ^ (rrow & 7);
            unsigned pk = (unsigned)f2bf(v) | ((unsigned)f2bf(po) << 16);
            *(unsigned*)(smem + rrow * 128 + (chunk << 3) + (rcol & 7)) = pk;
          }
        }
      }
    __syncthreads();
    unsigned short* O = z ? Kb : Qb;
    float* ss = sumsq + (long)z * SEQ;
#pragma unroll
    for (int round = 0; round < 8; ++round) {
      const int row = round * 16 + (tid >> 4);
      const int c = tid & 15;
      short8x vv = *(const short8x*)(smem + row * 128 + ((c ^ (row & 7)) << 3));
      *(short8x*)(O + (long)(m0 + row) * MID + n0 + c * 8) = vv;
      float s = 0.f;
#pragma unroll
      for (int j = 0; j < 8; ++j) { float f = bf2f((unsigned short)vv[j]); s += f * f; }
      s += __shfl_xor(s, 1); s += __shfl_xor(s, 2);
      s += __shfl_xor(s, 4); s += __shfl_xor(s, 8);
      if (c == 0) atomicAdd(ss + m0 + row, s);
    }
  } else {
    // V transposed: LDS tile [nn][mm]; lane holds 4 consecutive mm per (tile, reg-group)
#pragma unroll
    for (int tm = 0; tm < 2; ++tm)
#pragma unroll
      for (int tn = 0; tn < 2; ++tn) {
        const int nn = wn + tn * 32 + l31;
#pragma unroll
        for (int g = 0; g < 4; ++g) {
          const int mm = wm + tm * 32 + 8 * g + 4 * lh;
          const int chunk = (mm >> 3) ^ (nn & 7);
          ushort4 pk;
          pk.x = f2bf(acc[tm][tn][g * 4 + 0]);
          pk.y = f2bf(acc[tm][tn][g * 4 + 1]);
          pk.z = f2bf(acc[tm][tn][g * 4 + 2]);
          pk.w = f2bf(acc[tm][tn][g * 4 + 3]);
          *(ushort4*)(smem + nn * 128 + (chunk << 3) + (mm & 7)) = pk;
        }
      }
    __syncthreads();
#pragma unroll
    for (int round = 0; round < 8; ++round) {
      const int nn = round * 16 + (tid >> 4);
      const int c = tid & 15;
      short8x vv = *(const short8x*)(smem + nn * 128 + ((c ^ (nn & 7)) << 3));
      *(short8x*)(VT + (long)(n0 + nn) * SEQ + m0 + c * 8) = vv;
    }
  }
}

__global__ __launch_bounds__(256) void score_kernel(
    const unsigned short* __restrict__ Qb, const unsigned short* __restrict__ Kb,
    const float* __restrict__ sumsq,
    unsigned short* __restrict__ P, float* __restrict__ denom) {
  __shared__ unsigned short smem[16384];
  unsigned short* As = smem;
  unsigned short* Bs = smem + 8192;
  const int m0 = blockIdx.y * 128;
  const int n0 = blockIdx.x * 128;
  float16x acc[2][2];
#pragma unroll
  for (int i = 0; i < 2; ++i)
#pragma unroll
    for (int j = 0; j < 2; ++j)
#pragma unroll
      for (int e = 0; e < 16; ++e) acc[i][j][e] = 0.f;

  gemm128_nt(Qb, Kb, MID, MID, m0, n0, MID, As, Bs, acc);

  const int tid = threadIdx.x;
  const int l = tid & 63, w = tid >> 6;
  const int wm = (w & 1) << 6, wn = (w >> 1) << 6;
  const int l31 = l & 31, lh = l >> 5;

  // cosine normalization folded here
  float ik[2];
#pragma unroll
  for (int tn = 0; tn < 2; ++tn)
    ik[tn] = rsqrtf(sumsq[SEQ + n0 + wn + tn * 32 + l31]);

  __syncthreads();  // all waves done reading As/Bs

  // exp(scores*iq*ik) -> LDS tile [row][col] bf16, then full-line stores + row sums
#pragma unroll
  for (int tm = 0; tm < 2; ++tm)
#pragma unroll
    for (int r = 0; r < 16; ++r) {
      const int rrow = wm + tm * 32 + (r & 3) + 8 * (r >> 2) + 4 * lh;
      const float qi = rsqrtf(sumsq[m0 + rrow]);
#pragma unroll
      for (int tn = 0; tn < 2; ++tn) {
        float v = __expf(acc[tm][tn][r] * qi * ik[tn]);
        float po = __shfl_xor(v, 1);
        if (!(l & 1)) {
          const int rcol = wn + tn * 32 + l31;  // even
          const int chunk = (rcol >> 3) ^ (rrow & 7);
          unsigned pk = (unsigned)f2bf(v) | ((unsigned)f2bf(po) << 16);
          *(unsigned*)(smem + rrow * 128 + (chunk << 3) + (rcol & 7)) = pk;
        }
      }
    }
  __syncthreads();
#pragma unroll
  for (int round = 0; round < 8; ++round) {
    const int row = round * 16 + (tid >> 4);
    const int c = tid & 15;
    short8x vv = *(const short8x*)(smem + row * 128 + ((c ^ (row & 7)) << 3));
    *(short8x*)(P + (long)(m0 + row) * SEQ + n0 + c * 8) = vv;
    float s = 0.f;
#pragma unroll
    for (int j = 0; j < 8; ++j) s += bf2f((unsigned short)vv[j]);
    s += __shfl_xor(s, 1); s += __shfl_xor(s, 2);
    s += __shfl_xor(s, 4); s += __shfl_xor(s, 8);
    if (c == 0) atomicAdd(denom + m0 + row, s);
  }
}

__global__ __launch_bounds__(256) void out_kernel(
    const unsigned short* __restrict__ P, const unsigned short* __restrict__ VT,
    const float* __restrict__ denom, float* __restrict__ out) {
  __shared__ unsigned short smem[16384];
  unsigned short* As = smem;
  unsigned short* Bs = smem + 8192;
  // grid: x = m (fast, 64), y = n (8) -> the 8 n-blocks of one P-stripe share an XCD's L2
  const int m0 = blockIdx.x * 128;
  const int n0 = blockIdx.y * 128;
  float16x acc[2][2];
#pragma unroll
  for (int i = 0; i < 2; ++i)
#pragma unroll
    for (int j = 0; j < 2; ++j)
#pragma unroll
      for (int e = 0; e < 16; ++e) acc[i][j][e] = 0.f;

  gemm128_nt(P, VT, SEQ, SEQ, m0, n0, SEQ, As, Bs, acc);

  const int l = threadIdx.x & 63, w = threadIdx.x >> 6;
  const int wm = (w & 1) << 6, wn = (w >> 1) << 6;
  const int l31 = l & 31, lh = l >> 5;
#pragma unroll
  for (int tm = 0; tm < 2; ++tm)
#pragma unroll
    for (int r = 0; r < 16; ++r) {
      const int row = m0 + wm + tm * 32 + (r & 3) + 8 * (r >> 2) + 4 * lh;
      const float inv = 1.0f / denom[row];
#pragma unroll
      for (int tn = 0; tn < 2; ++tn) {
        const int col = n0 + wn + tn * 32 + l31;
        out[(long)row * MID + col] = acc[tm][tn][r] * inv;
      }
    }
}

extern "C" void kernel_launch(void* const* d_in, const int* in_sizes, int n_in,
                              void* d_out, int out_size, void* d_ws, size_t ws_size,
                              hipStream_t stream) {
  const float* X  = (const float*)d_in[0];
  const float* Wq = (const float*)d_in[1];
  const float* bq = (const float*)d_in[2];
  const float* Wk = (const float*)d_in[3];
  const float* bk = (const float*)d_in[4];
  const float* Wv = (const float*)d_in[5];
  const float* bv = (const float*)d_in[6];

  // workspace layout (bytes). Xb/Wb alias the P region: dead before score writes P.
  //  [0,16M)   Qb bf16 [8192][1024]   (unnormalized)
  //  [16M,32M) Kb bf16
  //  [32M,48M) VT bf16 [1024][8192]
  //  [48M,..)  sumsq_q[8192], sumsq_k[8192], denom[8192]  fp32
  //  [49M,177M) P bf16 [8192][8192];  Xb at 49M (16M), Wb at 65M (6M) alias inside
  char* wsb = (char*)d_ws;
  const size_t MB = 1ull << 20;
  unsigned short* Qb = (unsigned short*)(wsb);
  unsigned short* Kb = (unsigned short*)(wsb + 16 * MB);
  unsigned short* VT = (unsigned short*)(wsb + 32 * MB);
  float* sums        = (float*)(wsb + 48 * MB);
  float* denom       = sums + 2 * SEQ;
  unsigned short* P  = (unsigned short*)(wsb + 49 * MB);
  unsigned short* Xb = (unsigned short*)(wsb + 49 * MB);
  unsigned short* Wb = (unsigned short*)(wsb + 65 * MB);

  hipMemsetAsync(sums, 0, 3 * SEQ * sizeof(float), stream);

  cvt_kernel<<<SEQ * EMB / 1024, 256, 0, stream>>>(X, Xb, SEQ * EMB);
  cvtw_kernel<<<3 * MID * EMB / 1024, 256, 0, stream>>>(Wq, Wk, Wv, Wb);

  qkv_kernel<<<dim3(MID / 128, SEQ / 128, 3), 256, 0, stream>>>(Xb, Wb, bq, bk, bv, Qb, Kb, VT, sums);
  score_kernel<<<dim3(SEQ / 128, SEQ / 128), 256, 0, stream>>>(Qb, Kb, sums, P, denom);
  out_kernel<<<dim3(SEQ / 128, MID / 128), 256, 0, stream>>>(P, VT, denom, (float*)d_out);
}